// Round 10
// baseline (1004.554 us; speedup 1.0000x reference)
//
#include <hip/hip_runtime.h>
#include <stdint.h>

#define NROWS 131072
#define BM 64
#define NT 2
#define NBLK (NROWS / BM / NT)   // 1024
#define NK1 20
#define NK2 16
#define FSTR 1280
#define HSTR 1024
#define BUFSZ 81920

typedef __attribute__((ext_vector_type(8))) short bf16x8;
typedef __attribute__((ext_vector_type(4))) float f32x4;
typedef __attribute__((ext_vector_type(4))) int i32x4;
typedef __attribute__((ext_vector_type(2))) unsigned int u32x2;

__device__ __forceinline__ unsigned f2bf(float x) {
    union { float f; unsigned u; } v; v.f = x;
    unsigned r = v.u + 0x7FFFu + ((v.u >> 16) & 1u);
    return r >> 16;
}

// ws layout:
// [0, 655360)            W1 bf16 PACKED [wv8][ks20][cf4][lane64][8]
// [655360, 1179648)      W2 bf16 PACKED [wv8][ks16][cf4][lane64][8]
// [1179648, +2560)       wf[640] f32 (encode weights, cos folded to sin)
// [1182208, +2560)       bfv[640] f32 (encode biases, +pi/2 for cos)

__global__ void prep_kernel(
    const float* __restrict__ W1, const float* __restrict__ W2,
    const float* __restrict__ Wsx, const float* __restrict__ bsx,
    const float* __restrict__ Wcx, const float* __restrict__ bcx,
    const float* __restrict__ Wsy, const float* __restrict__ bsy,
    const float* __restrict__ Wcy, const float* __restrict__ bcy,
    const float* __restrict__ Wn, const float* __restrict__ bn,
    unsigned short* __restrict__ w1bp, unsigned short* __restrict__ w2bp,
    float* __restrict__ wf, float* __restrict__ bfv)
{
    int i = blockIdx.x * blockDim.x + threadIdx.x;
    const int n1 = 512 * 640;
    const int n2 = 512 * 512;
    if (i < n1) {
        int e = i & 7, g = i >> 3;
        int lane = g & 63, cf = (g >> 6) & 3;
        int wk = g >> 8;                 // wv*20 + ks
        int ks = wk % 20, wv = wk / 20;
        int col = wv * 64 + cf * 16 + (lane & 15);
        int k   = ks * 32 + (lane >> 4) * 8 + e;
        w1bp[i] = (unsigned short)f2bf(W1[col * 640 + k]);
    } else if (i < n1 + n2) {
        int ii = i - n1;
        int e = ii & 7, g = ii >> 3;
        int lane = g & 63, cf = (g >> 6) & 3;
        int ks = (g >> 8) & 15, wv = g >> 12;
        int col = wv * 64 + cf * 16 + (lane & 15);
        int k   = ks * 32 + (lane >> 4) * 8 + e;
        w2bp[ii] = (unsigned short)f2bf(W2[col * 512 + k]);
    }
    if (i < 640) {
        const float HPI = 1.57079632679489662f;
        float w, b;
        if (i < 512) {
            int j = i & 63, q = (i >> 6) & 3;
            if      (q == 0) { w = Wsx[j]; b = bsx[j]; }
            else if (q == 1) { w = Wcx[j]; b = bcx[j] + HPI; }
            else if (q == 2) { w = Wsy[j]; b = bsy[j]; }
            else             { w = Wcy[j]; b = bcy[j] + HPI; }
        } else { w = Wn[i - 512]; b = bn[i - 512]; }
        wf[i] = w; bfv[i] = b;
    }
}

// 768 threads = 8 GEMM waves (64 cols each) + 4 encode waves (4 thr/row).
// LDS: 2 x 80 KB feats buffers (dbuf across tiles); h aliases current buffer.

__global__ __launch_bounds__(768, 3) void mlp_kernel(
    const float* __restrict__ pf, const float* __restrict__ pt,
    const float* __restrict__ nm,
    const unsigned short* __restrict__ w1bp,
    const unsigned short* __restrict__ w2bp,
    const float* __restrict__ wf, const float* __restrict__ bfv,
    const float* __restrict__ b1, const float* __restrict__ b2,
    float* __restrict__ out)
{
    __shared__ __align__(16) unsigned char lds[2 * BUFSZ];

    const int tid  = threadIdx.x;
    const int lane = tid & 63;
    const int wave = tid >> 6;          // 0..7 GEMM, 8..11 encode
    const int l15  = lane & 15;
    const int l4   = lane >> 4;
    const int wcol = (wave & 7) * 64;
    const unsigned swz = (unsigned)((l15 & 7) << 4);
    const bool is_gemm = (wave < 8);

    // packed W streams (GEMM waves only dereference)
    const unsigned short* w1p = w1bp + (wave & 7) * (NK1 * 4 * 512) + lane * 8;
    const unsigned short* w2p = w2bp + (wave & 7) * (NK2 * 4 * 512) + lane * 8;
#define W1FRAG(KS, CF) (*(const bf16x8*)(w1p + ((KS) * 4 + (CF)) * 512))
#define W2FRAG(KS, CF) (*(const bf16x8*)(w2p + ((KS) * 4 + (CF)) * 512))

    // encode mapping (waves 8..11): 256 threads, 4 per row
    const int et   = tid & 255;
    const int erow = et >> 2;           // 0..63
    const int esub = et & 3;
    const unsigned eswz = (unsigned)((erow & 7) << 4);

    float v0 = 0.f, v1 = 0.f, v2 = 0.f, v3 = 0.f, v4 = 0.f;
#define LOADV(TAU) do {                                                            \
        const int grow_ = (blockIdx.x * NT + (TAU)) * BM + erow;                   \
        v0 = pf[grow_ * 2 + 0]; v1 = pf[grow_ * 2 + 1];                            \
        v2 = pt[grow_ * 2 + 0]; v3 = pt[grow_ * 2 + 1];                            \
        v4 = nm[grow_];                                                            \
    } while (0)

    // k = esub*8 + J*32 ; per-J segment uniform & compile-time; sin for J<16.
#define ENC_CHUNK(J, DST) do {                                                     \
        const int k_ = esub * 8 + (J) * 32;                                        \
        const float xv_ = ((J) < 4) ? v0 : ((J) < 8) ? v1 :                        \
                          ((J) < 12) ? v2 : ((J) < 16) ? v3 : v4;                  \
        const f32x4 w0_ = *(const f32x4*)(wf + k_);                                \
        const f32x4 w1_ = *(const f32x4*)(wf + k_ + 4);                            \
        const f32x4 c0_ = *(const f32x4*)(bfv + k_);                               \
        const f32x4 c1_ = *(const f32x4*)(bfv + k_ + 4);                           \
        float r_[8];                                                               \
        _Pragma("unroll")                                                          \
        for (int q_ = 0; q_ < 4; ++q_) {                                           \
            float a0_ = fmaf(xv_, w0_[q_], c0_[q_]);                               \
            float a1_ = fmaf(xv_, w1_[q_], c1_[q_]);                               \
            if ((J) < 16) { r_[q_] = __sinf(a0_); r_[q_ + 4] = __sinf(a1_); }      \
            else          { r_[q_] = a0_;         r_[q_ + 4] = a1_; }              \
        }                                                                          \
        i32x4 pk_;                                                                 \
        pk_.x = (int)(f2bf(r_[0]) | (f2bf(r_[1]) << 16));                          \
        pk_.y = (int)(f2bf(r_[2]) | (f2bf(r_[3]) << 16));                          \
        pk_.z = (int)(f2bf(r_[4]) | (f2bf(r_[5]) << 16));                          \
        pk_.w = (int)(f2bf(r_[6]) | (f2bf(r_[7]) << 16));                          \
        *(i32x4*)((DST) + erow * FSTR + (((unsigned)(k_ * 2)) ^ eswz)) = pk_;      \
    } while (0)

#define COMPUTE1(WB, KS, BUF) do {                                                 \
        _Pragma("unroll")                                                          \
        for (int rf = 0; rf < 4; ++rf) {                                           \
            bf16x8 af = *(const bf16x8*)((BUF) + (rf * 16 + l15) * FSTR +          \
                          (((unsigned)((KS) * 64 + l4 * 16)) ^ swz));              \
            _Pragma("unroll")                                                      \
            for (int cf = 0; cf < 4; ++cf)                                         \
                acc[rf][cf] = __builtin_amdgcn_mfma_f32_16x16x32_bf16(             \
                    WB[cf], af, acc[rf][cf], 0, 0, 0);                             \
        }                                                                          \
    } while (0)

#define COMPUTE2(WB, KS, BUF) do {                                                 \
        _Pragma("unroll")                                                          \
        for (int rf = 0; rf < 4; ++rf) {                                           \
            bf16x8 hf = *(const bf16x8*)((BUF) + (rf * 16 + l15) * HSTR +          \
                          (((unsigned)((KS) * 64 + l4 * 16)) ^ swz));              \
            _Pragma("unroll")                                                      \
            for (int cf = 0; cf < 4; ++cf)                                         \
                acc[rf][cf] = __builtin_amdgcn_mfma_f32_16x16x32_bf16(             \
                    WB[cf], hf, acc[rf][cf], 0, 0, 0);                             \
        }                                                                          \
    } while (0)

    f32x4 acc[4][4];
    #pragma unroll
    for (int a = 0; a < 4; ++a)
        #pragma unroll
        for (int b = 0; b < 4; ++b) acc[a][b] = (f32x4)(0.0f);

    // depth-4 rotating W-fragment buffers (GEMM waves)
    bf16x8 wb[4][4];

    // ---------------- prologue: encode T0; GEMM waves preload W1 frags ----------
    if (is_gemm) {
        #pragma unroll
        for (int t4 = 0; t4 < 4; ++t4)
            #pragma unroll
            for (int cf = 0; cf < 4; ++cf)
                wb[t4][cf] = W1FRAG(t4, cf);
    } else {
        LOADV(0);
        #pragma unroll
        for (int j = 0; j < 20; ++j) ENC_CHUNK(j, lds);
    }
    __syncthreads();

    for (int t = 0; t < NT; ++t) {
        unsigned char* bufc = lds + (unsigned)(t & 1) * BUFSZ;
        unsigned char* bufn = lds + (unsigned)((t & 1) ^ 1) * BUFSZ;
        const int rowbase = (blockIdx.x * NT + t) * BM;

        // ---- segment 1: GEMM1(t) || encode(t+1) chunks 0..6 ----
        if (is_gemm) {
            for (int ks2 = 0; ks2 < 5; ++ks2) {
                const int base = ks2 * 4;
                #pragma unroll
                for (int t4 = 0; t4 < 4; ++t4) {
                    const int ks = base + t4;
                    COMPUTE1(wb[t4], ks, bufc);
                    if (ks + 4 < NK1) {
                        #pragma unroll
                        for (int cf = 0; cf < 4; ++cf) wb[t4][cf] = W1FRAG(ks + 4, cf);
                    } else {
                        #pragma unroll
                        for (int cf = 0; cf < 4; ++cf) wb[t4][cf] = W2FRAG(ks + 4 - NK1, cf);
                    }
                }
            }
        } else if (t + 1 < NT) {
            LOADV(t + 1);
            #pragma unroll
            for (int j = 0; j < 7; ++j) ENC_CHUNK(j, bufn);
        }
        __syncthreads();   // GEMM1 reads of bufc done; h may alias bufc

        // ---- segment 2: bias+leaky -> h in bufc || encode chunks 7..13 ----
        if (is_gemm) {
            #pragma unroll
            for (int cf = 0; cf < 4; ++cf) {
                const int colb = wcol + cf * 16 + l4 * 4;
                const f32x4 bb = *(const f32x4*)(b1 + colb);
                #pragma unroll
                for (int rf = 0; rf < 4; ++rf) {
                    const int row = rf * 16 + l15;
                    float h0 = acc[rf][cf][0] + bb[0];
                    float h1 = acc[rf][cf][1] + bb[1];
                    float h2 = acc[rf][cf][2] + bb[2];
                    float h3 = acc[rf][cf][3] + bb[3];
                    h0 = (h0 >= 0.f) ? h0 : 0.01f * h0;
                    h1 = (h1 >= 0.f) ? h1 : 0.01f * h1;
                    h2 = (h2 >= 0.f) ? h2 : 0.01f * h2;
                    h3 = (h3 >= 0.f) ? h3 : 0.01f * h3;
                    u32x2 pk;
                    pk.x = f2bf(h0) | (f2bf(h1) << 16);
                    pk.y = f2bf(h2) | (f2bf(h3) << 16);
                    *(u32x2*)(bufc + row * HSTR + (((unsigned)(colb * 2)) ^ swz)) = pk;
                }
            }
            #pragma unroll
            for (int a = 0; a < 4; ++a)
                #pragma unroll
                for (int b = 0; b < 4; ++b) acc[a][b] = (f32x4)(0.0f);
        } else if (t + 1 < NT) {
            #pragma unroll
            for (int j = 7; j < 14; ++j) ENC_CHUNK(j, bufn);
        }
        __syncthreads();   // h visible to all GEMM waves

        // ---- segment 3: GEMM2(t) + store || encode chunks 14..19 ----
        if (is_gemm) {
            for (int ks2 = 0; ks2 < 4; ++ks2) {
                const int base = ks2 * 4;
                #pragma unroll
                for (int t4 = 0; t4 < 4; ++t4) {
                    const int ks = base + t4;
                    COMPUTE2(wb[t4], ks, bufc);
                    if (ks + 4 < NK2) {
                        #pragma unroll
                        for (int cf = 0; cf < 4; ++cf) wb[t4][cf] = W2FRAG(ks + 4, cf);
                    } else {
                        #pragma unroll
                        for (int cf = 0; cf < 4; ++cf) wb[t4][cf] = W1FRAG(ks + 4 - NK2, cf);
                    }
                }
            }
            #pragma unroll
            for (int cf = 0; cf < 4; ++cf) {
                const int colb = wcol + cf * 16 + l4 * 4;
                const f32x4 bb = *(const f32x4*)(b2 + colb);
                #pragma unroll
                for (int rf = 0; rf < 4; ++rf) {
                    const int row = rowbase + rf * 16 + l15;
                    f32x4 o = acc[rf][cf] + bb;
                    *(f32x4*)(out + row * 512 + colb) = o;
                }
            }
            #pragma unroll
            for (int a = 0; a < 4; ++a)
                #pragma unroll
                for (int b = 0; b < 4; ++b) acc[a][b] = (f32x4)(0.0f);
        } else if (t + 1 < NT) {
            #pragma unroll
            for (int j = 14; j < 20; ++j) ENC_CHUNK(j, bufn);
        }
        __syncthreads();   // bufn complete; bufc free for next producer round
    }
}

extern "C" void kernel_launch(void* const* d_in, const int* in_sizes, int n_in,
                              void* d_out, int out_size, void* d_ws, size_t ws_size,
                              hipStream_t stream)
{
    (void)in_sizes; (void)n_in; (void)out_size; (void)ws_size;
    const float* pf  = (const float*)d_in[0];
    const float* pt  = (const float*)d_in[1];
    const float* nm  = (const float*)d_in[2];
    const float* Wsx = (const float*)d_in[3];
    const float* bsx = (const float*)d_in[4];
    const float* Wcx = (const float*)d_in[5];
    const float* bcx = (const float*)d_in[6];
    const float* Wsy = (const float*)d_in[7];
    const float* bsy = (const float*)d_in[8];
    const float* Wcy = (const float*)d_in[9];
    const float* bcy = (const float*)d_in[10];
    const float* Wn  = (const float*)d_in[11];
    const float* bn  = (const float*)d_in[12];
    const float* W1  = (const float*)d_in[13];
    const float* b1  = (const float*)d_in[14];
    const float* W2  = (const float*)d_in[15];
    const float* b2  = (const float*)d_in[16];

    unsigned char* ws = (unsigned char*)d_ws;
    unsigned short* w1bp = (unsigned short*)(ws);
    unsigned short* w2bp = (unsigned short*)(ws + 512 * 640 * 2);
    float* wf  = (float*)(ws + 512 * 640 * 2 + 512 * 512 * 2);
    float* bfv = (float*)(ws + 512 * 640 * 2 + 512 * 512 * 2 + 640 * 4);

    const int prep_threads = 512 * 640 + 512 * 512;
    prep_kernel<<<(prep_threads + 255) / 256, 256, 0, stream>>>(
        W1, W2, Wsx, bsx, Wcx, bcx, Wsy, bsy, Wcy, bcy, Wn, bn, w1bp, w2bp, wf, bfv);

    mlp_kernel<<<NBLK, 768, 0, stream>>>(
        pf, pt, nm, w1bp, w2bp, wf, bfv, b1, b2, (float*)d_out);
}

// Round 11
// 209.616 us; speedup vs baseline: 4.7924x; 4.7924x over previous
//
#include <hip/hip_runtime.h>
#include <stdint.h>

#define NROWS 131072
#define BM 64
#define NT 2
#define NBLK (NROWS / BM / NT)   // 1024
#define NK1 20
#define NK2 16
#define FSTR 1280
#define HSTR 1024
#define BUFSZ 81920

typedef __attribute__((ext_vector_type(8))) short bf16x8;
typedef __attribute__((ext_vector_type(4))) float f32x4;
typedef __attribute__((ext_vector_type(4))) int i32x4;
typedef __attribute__((ext_vector_type(2))) unsigned int u32x2;

__device__ __forceinline__ unsigned f2bf(float x) {
    union { float f; unsigned u; } v; v.f = x;
    unsigned r = v.u + 0x7FFFu + ((v.u >> 16) & 1u);
    return r >> 16;
}

// ws layout:
// [0, 655360)            W1 bf16 PACKED [wv8][ks20][cf4][lane64][8]
// [655360, 1179648)      W2 bf16 PACKED [wv8][ks16][cf4][lane64][8]
// [1179648, +2560)       wf[640] f32 (encode weights, cos folded to sin)
// [1182208, +2560)       bfv[640] f32 (encode biases, +pi/2 for cos)

__global__ void prep_kernel(
    const float* __restrict__ W1, const float* __restrict__ W2,
    const float* __restrict__ Wsx, const float* __restrict__ bsx,
    const float* __restrict__ Wcx, const float* __restrict__ bcx,
    const float* __restrict__ Wsy, const float* __restrict__ bsy,
    const float* __restrict__ Wcy, const float* __restrict__ bcy,
    const float* __restrict__ Wn, const float* __restrict__ bn,
    unsigned short* __restrict__ w1bp, unsigned short* __restrict__ w2bp,
    float* __restrict__ wf, float* __restrict__ bfv)
{
    int i = blockIdx.x * blockDim.x + threadIdx.x;
    const int n1 = 512 * 640;
    const int n2 = 512 * 512;
    if (i < n1) {
        int e = i & 7, g = i >> 3;
        int lane = g & 63, cf = (g >> 6) & 3;
        int wk = g >> 8;                 // wv*20 + ks
        int ks = wk % 20, wv = wk / 20;
        int col = wv * 64 + cf * 16 + (lane & 15);
        int k   = ks * 32 + (lane >> 4) * 8 + e;
        w1bp[i] = (unsigned short)f2bf(W1[col * 640 + k]);
    } else if (i < n1 + n2) {
        int ii = i - n1;
        int e = ii & 7, g = ii >> 3;
        int lane = g & 63, cf = (g >> 6) & 3;
        int ks = (g >> 8) & 15, wv = g >> 12;
        int col = wv * 64 + cf * 16 + (lane & 15);
        int k   = ks * 32 + (lane >> 4) * 8 + e;
        w2bp[ii] = (unsigned short)f2bf(W2[col * 512 + k]);
    }
    if (i < 640) {
        const float HPI = 1.57079632679489662f;
        float w, b;
        if (i < 512) {
            int j = i & 63, q = (i >> 6) & 3;
            if      (q == 0) { w = Wsx[j]; b = bsx[j]; }
            else if (q == 1) { w = Wcx[j]; b = bcx[j] + HPI; }
            else if (q == 2) { w = Wsy[j]; b = bsy[j]; }
            else             { w = Wcy[j]; b = bcy[j] + HPI; }
        } else { w = Wn[i - 512]; b = bn[i - 512]; }
        wf[i] = w; bfv[i] = b;
    }
}

// 512 threads, 8 waves x 64 out-cols, BM=64, NT=2 tiles/block.
// LDS: two 80-KB feats buffers; h [64][512] aliases the current buffer.

__global__ __launch_bounds__(512, 1) void mlp_kernel(
    const float* __restrict__ pf, const float* __restrict__ pt,
    const float* __restrict__ nm,
    const unsigned short* __restrict__ w1bp,
    const unsigned short* __restrict__ w2bp,
    const float* __restrict__ wf, const float* __restrict__ bfv,
    const float* __restrict__ b1, const float* __restrict__ b2,
    float* __restrict__ out)
{
    __shared__ __align__(16) unsigned char lds[2 * BUFSZ];

    const int tid  = threadIdx.x;
    const int lane = tid & 63;
    const int wave = tid >> 6;          // 0..7, each owns 64 output cols
    const int l15  = lane & 15;
    const int l4   = lane >> 4;
    const int wcol = wave * 64;
    const unsigned swz = (unsigned)((l15 & 7) << 4);

    const unsigned short* w1p = w1bp + wave * (NK1 * 4 * 512) + lane * 8;
    const unsigned short* w2p = w2bp + wave * (NK2 * 4 * 512) + lane * 8;
#define W1FRAG(KS, CF) (*(const bf16x8*)(w1p + ((KS) * 4 + (CF)) * 512))
#define W2FRAG(KS, CF) (*(const bf16x8*)(w2p + ((KS) * 4 + (CF)) * 512))

    // encode mapping: 8 threads/row, k = esub*8 + j*64 (conflict-free slots)
    const int erow = tid >> 3;          // 0..63
    const int esub = tid & 7;
    const unsigned eswz = (unsigned)((erow & 7) << 4);

    float v0, v1, v2, v3, v4;
#define LOADV(TAU) do {                                                            \
        const int grow_ = (blockIdx.x * NT + (TAU)) * BM + erow;                   \
        v0 = pf[grow_ * 2 + 0]; v1 = pf[grow_ * 2 + 1];                            \
        v2 = pt[grow_ * 2 + 0]; v3 = pt[grow_ * 2 + 1];                            \
        v4 = nm[grow_];                                                            \
    } while (0)

    // j0,1->pf.x j2,3->pf.y j4,5->pt.x j6,7->pt.y j8,9->numbers ; sin for j<8.
#define ENC_CHUNK(J, DST) do {                                                     \
        const int k_ = esub * 8 + (J) * 64;                                        \
        const float xv_ = ((J) < 2) ? v0 : ((J) < 4) ? v1 :                        \
                          ((J) < 6) ? v2 : ((J) < 8) ? v3 : v4;                    \
        const f32x4 w0_ = *(const f32x4*)(wf + k_);                                \
        const f32x4 w1_ = *(const f32x4*)(wf + k_ + 4);                            \
        const f32x4 c0_ = *(const f32x4*)(bfv + k_);                               \
        const f32x4 c1_ = *(const f32x4*)(bfv + k_ + 4);                           \
        float r_[8];                                                               \
        _Pragma("unroll")                                                          \
        for (int q_ = 0; q_ < 4; ++q_) {                                           \
            float a0_ = fmaf(xv_, w0_[q_], c0_[q_]);                               \
            float a1_ = fmaf(xv_, w1_[q_], c1_[q_]);                               \
            if ((J) < 8) { r_[q_] = __sinf(a0_); r_[q_ + 4] = __sinf(a1_); }       \
            else         { r_[q_] = a0_;         r_[q_ + 4] = a1_; }               \
        }                                                                          \
        i32x4 pk_;                                                                 \
        pk_.x = (int)(f2bf(r_[0]) | (f2bf(r_[1]) << 16));                          \
        pk_.y = (int)(f2bf(r_[2]) | (f2bf(r_[3]) << 16));                          \
        pk_.z = (int)(f2bf(r_[4]) | (f2bf(r_[5]) << 16));                          \
        pk_.w = (int)(f2bf(r_[6]) | (f2bf(r_[7]) << 16));                          \
        *(i32x4*)((DST) + erow * FSTR + (((unsigned)(k_ * 2)) ^ eswz)) = pk_;      \
    } while (0)

#define COMPUTE1(WB, KS, BUF) do {                                                 \
        _Pragma("unroll")                                                          \
        for (int rf = 0; rf < 4; ++rf) {                                           \
            bf16x8 af = *(const bf16x8*)((BUF) + (rf * 16 + l15) * FSTR +          \
                          (((unsigned)((KS) * 64 + l4 * 16)) ^ swz));              \
            _Pragma("unroll")                                                      \
            for (int cf = 0; cf < 4; ++cf)                                         \
                acc[rf][cf] = __builtin_amdgcn_mfma_f32_16x16x32_bf16(             \
                    WB[cf], af, acc[rf][cf], 0, 0, 0);                             \
        }                                                                          \
    } while (0)

#define COMPUTE2(WB, KS, BUF) do {                                                 \
        _Pragma("unroll")                                                          \
        for (int rf = 0; rf < 4; ++rf) {                                           \
            bf16x8 hf = *(const bf16x8*)((BUF) + (rf * 16 + l15) * HSTR +          \
                          (((unsigned)((KS) * 64 + l4 * 16)) ^ swz));              \
            _Pragma("unroll")                                                      \
            for (int cf = 0; cf < 4; ++cf)                                         \
                acc[rf][cf] = __builtin_amdgcn_mfma_f32_16x16x32_bf16(             \
                    WB[cf], hf, acc[rf][cf], 0, 0, 0);                             \
        }                                                                          \
    } while (0)

    f32x4 acc[4][4];
    #pragma unroll
    for (int a = 0; a < 4; ++a)
        #pragma unroll
        for (int b = 0; b < 4; ++b) acc[a][b] = (f32x4)(0.0f);

    // depth-4 rotating W-fragment buffers
    bf16x8 wb[4][4];
    #pragma unroll
    for (int t4 = 0; t4 < 4; ++t4)
        #pragma unroll
        for (int cf = 0; cf < 4; ++cf)
            wb[t4][cf] = W1FRAG(t4, cf);

    // prologue: encode tile 0 -> buf0; preload v for tile 1
    LOADV(0);
    #pragma unroll
    for (int j = 0; j < 10; ++j) ENC_CHUNK(j, lds);
    LOADV(1);
    __syncthreads();

    #pragma unroll
    for (int t = 0; t < NT; ++t) {
        unsigned char* bufc = lds + (unsigned)(t & 1) * BUFSZ;
        unsigned char* bufn = lds + (unsigned)((t & 1) ^ 1) * BUFSZ;
        const int rowbase = (blockIdx.x * NT + t) * BM;

        // ---- GEMM1(t) from bufc; encode(t+1) chunk per ks2 -> bufn ----
        #pragma unroll
        for (int ks2 = 0; ks2 < 10; ++ks2) {
            const int ksA = 2 * ks2;
            __builtin_amdgcn_s_setprio(1);
            COMPUTE1(wb[ksA & 3], ksA, bufc);
            __builtin_amdgcn_s_setprio(0);
            {
                const int ks = ksA;
                if (ks + 4 < NK1) {
                    #pragma unroll
                    for (int cf = 0; cf < 4; ++cf) wb[ks & 3][cf] = W1FRAG(ks + 4, cf);
                } else {
                    #pragma unroll
                    for (int cf = 0; cf < 4; ++cf) wb[ks & 3][cf] = W2FRAG(ks + 4 - NK1, cf);
                }
            }
            if (t + 1 < NT) ENC_CHUNK(ks2, bufn);
            __builtin_amdgcn_s_setprio(1);
            COMPUTE1(wb[(ksA + 1) & 3], ksA + 1, bufc);
            __builtin_amdgcn_s_setprio(0);
            {
                const int ks = ksA + 1;
                if (ks + 4 < NK1) {
                    #pragma unroll
                    for (int cf = 0; cf < 4; ++cf) wb[ks & 3][cf] = W1FRAG(ks + 4, cf);
                } else {
                    #pragma unroll
                    for (int cf = 0; cf < 4; ++cf) wb[ks & 3][cf] = W2FRAG(ks + 4 - NK1, cf);
                }
            }
        }

        __syncthreads();   // GEMM1 reads of bufc done; encode(t+1) complete

        // ---- bias + leaky -> h in bufc ----
        #pragma unroll
        for (int cf = 0; cf < 4; ++cf) {
            const int colb = wcol + cf * 16 + l4 * 4;
            const f32x4 bb = *(const f32x4*)(b1 + colb);
            #pragma unroll
            for (int rf = 0; rf < 4; ++rf) {
                const int row = rf * 16 + l15;
                float h0 = acc[rf][cf][0] + bb[0];
                float h1 = acc[rf][cf][1] + bb[1];
                float h2 = acc[rf][cf][2] + bb[2];
                float h3 = acc[rf][cf][3] + bb[3];
                h0 = (h0 >= 0.f) ? h0 : 0.01f * h0;
                h1 = (h1 >= 0.f) ? h1 : 0.01f * h1;
                h2 = (h2 >= 0.f) ? h2 : 0.01f * h2;
                h3 = (h3 >= 0.f) ? h3 : 0.01f * h3;
                u32x2 pk;
                pk.x = f2bf(h0) | (f2bf(h1) << 16);
                pk.y = f2bf(h2) | (f2bf(h3) << 16);
                *(u32x2*)(bufc + row * HSTR + (((unsigned)(colb * 2)) ^ swz)) = pk;
            }
        }

        #pragma unroll
        for (int a = 0; a < 4; ++a)
            #pragma unroll
            for (int b = 0; b < 4; ++b) acc[a][b] = (f32x4)(0.0f);

        __syncthreads();   // h visible

        // ---- GEMM2(t) from bufc; tail rotates into next tile's W1 ----
        #pragma unroll
        for (int ks2 = 0; ks2 < 8; ++ks2) {
            const int ksA = 2 * ks2;
            __builtin_amdgcn_s_setprio(1);
            COMPUTE2(wb[ksA & 3], ksA, bufc);
            __builtin_amdgcn_s_setprio(0);
            {
                const int ks = ksA;
                if (ks + 4 < NK2) {
                    #pragma unroll
                    for (int cf = 0; cf < 4; ++cf) wb[ks & 3][cf] = W2FRAG(ks + 4, cf);
                } else {
                    #pragma unroll
                    for (int cf = 0; cf < 4; ++cf) wb[ks & 3][cf] = W1FRAG(ks + 4 - NK2, cf);
                }
            }
            __builtin_amdgcn_s_setprio(1);
            COMPUTE2(wb[(ksA + 1) & 3], ksA + 1, bufc);
            __builtin_amdgcn_s_setprio(0);
            {
                const int ks = ksA + 1;
                if (ks + 4 < NK2) {
                    #pragma unroll
                    for (int cf = 0; cf < 4; ++cf) wb[ks & 3][cf] = W2FRAG(ks + 4, cf);
                } else {
                    #pragma unroll
                    for (int cf = 0; cf < 4; ++cf) wb[ks & 3][cf] = W1FRAG(ks + 4 - NK2, cf);
                }
            }
        }

        // ---- store(t): bias + float4, fire-and-forget ----
        #pragma unroll
        for (int cf = 0; cf < 4; ++cf) {
            const int colb = wcol + cf * 16 + l4 * 4;
            const f32x4 bb = *(const f32x4*)(b2 + colb);
            #pragma unroll
            for (int rf = 0; rf < 4; ++rf) {
                const int row = rowbase + rf * 16 + l15;
                f32x4 o = acc[rf][cf] + bb;
                *(f32x4*)(out + row * 512 + colb) = o;
            }
        }

        #pragma unroll
        for (int a = 0; a < 4; ++a)
            #pragma unroll
            for (int b = 0; b < 4; ++b) acc[a][b] = (f32x4)(0.0f);
        // no barrier needed: GEMM1(t+1) reads bufn (already barriered);
        // h(t+1) write to bufn comes only after GEMM1(t+1)'s own barrier.
    }
}

extern "C" void kernel_launch(void* const* d_in, const int* in_sizes, int n_in,
                              void* d_out, int out_size, void* d_ws, size_t ws_size,
                              hipStream_t stream)
{
    (void)in_sizes; (void)n_in; (void)out_size; (void)ws_size;
    const float* pf  = (const float*)d_in[0];
    const float* pt  = (const float*)d_in[1];
    const float* nm  = (const float*)d_in[2];
    const float* Wsx = (const float*)d_in[3];
    const float* bsx = (const float*)d_in[4];
    const float* Wcx = (const float*)d_in[5];
    const float* bcx = (const float*)d_in[6];
    const float* Wsy = (const float*)d_in[7];
    const float* bsy = (const float*)d_in[8];
    const float* Wcy = (const float*)d_in[9];
    const float* bcy = (const float*)d_in[10];
    const float* Wn  = (const float*)d_in[11];
    const float* bn  = (const float*)d_in[12];
    const float* W1  = (const float*)d_in[13];
    const float* b1  = (const float*)d_in[14];
    const float* W2  = (const float*)d_in[15];
    const float* b2  = (const float*)d_in[16];

    unsigned char* ws = (unsigned char*)d_ws;
    unsigned short* w1bp = (unsigned short*)(ws);
    unsigned short* w2bp = (unsigned short*)(ws + 512 * 640 * 2);
    float* wf  = (float*)(ws + 512 * 640 * 2 + 512 * 512 * 2);
    float* bfv = (float*)(ws + 512 * 640 * 2 + 512 * 512 * 2 + 640 * 4);

    const int prep_threads = 512 * 640 + 512 * 512;
    prep_kernel<<<(prep_threads + 255) / 256, 256, 0, stream>>>(
        W1, W2, Wsx, bsx, Wcx, bcx, Wsy, bsy, Wcy, bcy, Wn, bn, w1bp, w2bp, wf, bfv);

    mlp_kernel<<<NBLK, 512, 0, stream>>>(
        pf, pt, nm, w1bp, w2bp, wf, bfv, b1, b2, (float*)d_out);
}

// Round 12
// 182.186 us; speedup vs baseline: 5.5139x; 1.1506x over previous
//
#include <hip/hip_runtime.h>
#include <hip/hip_bf16.h>
#include <stdint.h>

#define NROWS 131072
#define BM 128
#define NK1 20
#define NK2 16
#define FSTR 1280
#define HSTR 1024

typedef __attribute__((ext_vector_type(8))) short bf16x8;
typedef __attribute__((ext_vector_type(4))) float f32x4;
typedef __attribute__((ext_vector_type(4))) int i32x4;
typedef __attribute__((ext_vector_type(2))) unsigned int u32x2;

__device__ __forceinline__ unsigned f2bf(float x) {
    union { float f; unsigned u; } v; v.f = x;
    unsigned r = v.u + 0x7FFFu + ((v.u >> 16) & 1u);
    return r >> 16;
}

// pack two f32 -> one u32 of 2 bf16 (compiler emits v_cvt_pk_bf16_f32)
__device__ __forceinline__ unsigned pk2(float a, float b) {
    float2 t; t.x = a; t.y = b;
    __hip_bfloat162 h = __float22bfloat162_rn(t);
    union { __hip_bfloat162 h; unsigned u; } c; c.h = h;
    return c.u;
}

// ws layout:
// [0, 655360)            W1 bf16 PACKED [wv8][ks20][cf4][lane64][8]
// [655360, 1179648)      W2 bf16 PACKED [wv8][ks16][cf4][lane64][8]
// [1179648, +2560)       wf[640] f32 (encode weights; trig rows pre-scaled by 1/2pi)
// [1182208, +2560)       bfv[640] f32 (encode biases; cos folded, pre-scaled)

__global__ void prep_kernel(
    const float* __restrict__ W1, const float* __restrict__ W2,
    const float* __restrict__ Wsx, const float* __restrict__ bsx,
    const float* __restrict__ Wcx, const float* __restrict__ bcx,
    const float* __restrict__ Wsy, const float* __restrict__ bsy,
    const float* __restrict__ Wcy, const float* __restrict__ bcy,
    const float* __restrict__ Wn, const float* __restrict__ bn,
    unsigned short* __restrict__ w1bp, unsigned short* __restrict__ w2bp,
    float* __restrict__ wf, float* __restrict__ bfv)
{
    int i = blockIdx.x * blockDim.x + threadIdx.x;
    const int n1 = 512 * 640;
    const int n2 = 512 * 512;
    if (i < n1) {
        int e = i & 7, g = i >> 3;
        int lane = g & 63, cf = (g >> 6) & 3;
        int wk = g >> 8;                 // wv*20 + ks
        int ks = wk % 20, wv = wk / 20;
        int col = wv * 64 + cf * 16 + (lane & 15);
        int k   = ks * 32 + (lane >> 4) * 8 + e;
        w1bp[i] = (unsigned short)f2bf(W1[col * 640 + k]);
    } else if (i < n1 + n2) {
        int ii = i - n1;
        int e = ii & 7, g = ii >> 3;
        int lane = g & 63, cf = (g >> 6) & 3;
        int ks = (g >> 8) & 15, wv = g >> 12;
        int col = wv * 64 + cf * 16 + (lane & 15);
        int k   = ks * 32 + (lane >> 4) * 8 + e;
        w2bp[ii] = (unsigned short)f2bf(W2[col * 512 + k]);
    }
    if (i < 640) {
        const float HPI = 1.57079632679489662f;
        const float INV2PI = 0.15915494309189535f;   // 1/(2*pi)
        float w, b;
        if (i < 512) {
            int j = i & 63, q = (i >> 6) & 3;
            if      (q == 0) { w = Wsx[j]; b = bsx[j]; }
            else if (q == 1) { w = Wcx[j]; b = bcx[j] + HPI; }  // cos(a)=sin(a+pi/2)
            else if (q == 2) { w = Wsy[j]; b = bsy[j]; }
            else             { w = Wcy[j]; b = bcy[j] + HPI; }
            // pre-scale to revolutions: sin(a) = v_sin_f32(a/2pi); |a|<=2 so no reduction
            w *= INV2PI; b *= INV2PI;
        } else { w = Wn[i - 512]; b = bn[i - 512]; }
        wf[i] = w; bfv[i] = b;
    }
}

// LDS: feats [128][640] bf16, stride 1280 B, byte-XOR ((row&15)<<4) = 163840 B
//      h     [128][512] bf16, stride 1024 B, same XOR (aliased at base)
// 4-bit swizzle: rows r and r+8 land in different 16B slots (stride%128==0 fix).

__global__ __launch_bounds__(512, 1) void mlp_kernel(
    const float* __restrict__ pf, const float* __restrict__ pt,
    const float* __restrict__ nm,
    const unsigned short* __restrict__ w1bp,
    const unsigned short* __restrict__ w2bp,
    const float* __restrict__ wf, const float* __restrict__ bfv,
    const float* __restrict__ b1, const float* __restrict__ b2,
    float* __restrict__ out)
{
    __shared__ __align__(16) unsigned char lds[163840];

    const int tid  = threadIdx.x;
    const int lane = tid & 63;
    const int wave = tid >> 6;          // 0..7, each owns 64 output cols
    const int l15  = lane & 15;
    const int l4   = lane >> 4;         // 0..3
    const int rowbase = blockIdx.x * BM;
    const int wcol = wave * 64;
    const unsigned swz = (unsigned)(l15 << 4);   // row&15 == l15 for all GEMM rows

    // PACKED W streams: per (ks,cf) one contiguous 1-KB fragment block.
    const unsigned short* w1p = w1bp + wave * (NK1 * 4 * 512) + lane * 8;
    const unsigned short* w2p = w2bp + wave * (NK2 * 4 * 512) + lane * 8;
#define W1FRAG(KS, CF) (*(const bf16x8*)(w1p + ((KS) * 4 + (CF)) * 512))
#define W2FRAG(KS, CF) (*(const bf16x8*)(w2p + ((KS) * 4 + (CF)) * 512))

    // depth-4 rotating register buffers for W fragments
    bf16x8 wb[4][4];
    #pragma unroll
    for (int t = 0; t < 4; ++t)
        #pragma unroll
        for (int cf = 0; cf < 4; ++cf)
            wb[t][cf] = W1FRAG(t, cf);

    // ---------------- encode: 4 threads/row, k = esub*8 + j*32 ----------------
    // Per-j segment uniform & compile-time: j0-3 pf.x | j4-7 pf.y | j8-11 pt.x |
    // j12-15 pt.y | j16-19 numbers ; native v_sin for j<16 (pre-scaled table).
    {
        const int erow = tid >> 2;          // 0..127
        const int esub = tid & 3;
        const int grow = rowbase + erow;
        const float v0 = pf[grow * 2 + 0];
        const float v1 = pf[grow * 2 + 1];
        const float v2 = pt[grow * 2 + 0];
        const float v3 = pt[grow * 2 + 1];
        const float v4 = nm[grow];
        const unsigned eswz = (unsigned)((erow & 15) << 4);
        #pragma unroll
        for (int j = 0; j < 20; ++j) {
            const int k = esub * 8 + j * 32;
            const float xv = (j < 4) ? v0 : (j < 8) ? v1 :
                             (j < 12) ? v2 : (j < 16) ? v3 : v4;
            const f32x4 w0 = *(const f32x4*)(wf + k);
            const f32x4 w1v = *(const f32x4*)(wf + k + 4);
            const f32x4 c0 = *(const f32x4*)(bfv + k);
            const f32x4 c1 = *(const f32x4*)(bfv + k + 4);
            float r[8];
            #pragma unroll
            for (int t = 0; t < 4; ++t) {
                float a0 = fmaf(xv, w0[t], c0[t]);
                float a1 = fmaf(xv, w1v[t], c1[t]);
                if (j < 16) {
                    asm("v_sin_f32 %0, %1" : "=v"(r[t])     : "v"(a0));
                    asm("v_sin_f32 %0, %1" : "=v"(r[t + 4]) : "v"(a1));
                } else { r[t] = a0; r[t + 4] = a1; }
            }
            i32x4 pk;
            pk.x = (int)pk2(r[0], r[1]);
            pk.y = (int)pk2(r[2], r[3]);
            pk.z = (int)pk2(r[4], r[5]);
            pk.w = (int)pk2(r[6], r[7]);
            *(i32x4*)(lds + erow * FSTR + (((unsigned)(k * 2)) ^ eswz)) = pk;
        }
    }

    f32x4 acc[8][4];
    #pragma unroll
    for (int a = 0; a < 8; ++a)
        #pragma unroll
        for (int b = 0; b < 4; ++b) acc[a][b] = (f32x4)(0.0f);

    __syncthreads();

    // ---------------- layer 1: K=640, free-running depth-4 pipeline ----------------
    for (int ks2 = 0; ks2 < 5; ++ks2) {
        const int base = ks2 * 4;
        #pragma unroll
        for (int t = 0; t < 4; ++t) {
            const int ks = base + t;
            #pragma unroll
            for (int rf = 0; rf < 8; ++rf) {
                bf16x8 af = *(const bf16x8*)(lds + (rf * 16 + l15) * FSTR +
                              (((unsigned)(ks * 64 + l4 * 16)) ^ swz));
                #pragma unroll
                for (int cf = 0; cf < 4; ++cf)
                    acc[rf][cf] = __builtin_amdgcn_mfma_f32_16x16x32_bf16(
                        wb[t][cf], af, acc[rf][cf], 0, 0, 0);
            }
            if (ks + 4 < NK1) {
                #pragma unroll
                for (int cf = 0; cf < 4; ++cf)
                    wb[t][cf] = W1FRAG(ks + 4, cf);
            }
        }
    }

    // prologue W2 loads — latency hidden under h-epilogue + barrier
    #pragma unroll
    for (int t = 0; t < 4; ++t)
        #pragma unroll
        for (int cf = 0; cf < 4; ++cf)
            wb[t][cf] = W2FRAG(t, cf);

    __syncthreads();   // all feats reads done; h may alias feats

    // ---------------- bias + leaky -> h (bf16, 8B LDS writes) ----------------
    #pragma unroll
    for (int cf = 0; cf < 4; ++cf) {
        const int colb = wcol + cf * 16 + l4 * 4;
        const f32x4 bb = *(const f32x4*)(b1 + colb);
        #pragma unroll
        for (int rf = 0; rf < 8; ++rf) {
            const int row = rf * 16 + l15;
            float h0 = acc[rf][cf][0] + bb[0];
            float h1 = acc[rf][cf][1] + bb[1];
            float h2 = acc[rf][cf][2] + bb[2];
            float h3 = acc[rf][cf][3] + bb[3];
            h0 = (h0 >= 0.f) ? h0 : 0.01f * h0;
            h1 = (h1 >= 0.f) ? h1 : 0.01f * h1;
            h2 = (h2 >= 0.f) ? h2 : 0.01f * h2;
            h3 = (h3 >= 0.f) ? h3 : 0.01f * h3;
            u32x2 pk;
            pk.x = pk2(h0, h1);
            pk.y = pk2(h2, h3);
            *(u32x2*)(lds + row * HSTR + (((unsigned)(colb * 2)) ^ swz)) = pk;
        }
    }

    #pragma unroll
    for (int a = 0; a < 8; ++a)
        #pragma unroll
        for (int b = 0; b < 4; ++b) acc[a][b] = (f32x4)(0.0f);

    __syncthreads();

    // ---------------- layer 2: K=512, same pipeline ----------------
    for (int ks2 = 0; ks2 < 4; ++ks2) {
        const int base = ks2 * 4;
        #pragma unroll
        for (int t = 0; t < 4; ++t) {
            const int ks = base + t;
            #pragma unroll
            for (int rf = 0; rf < 8; ++rf) {
                bf16x8 hf = *(const bf16x8*)(lds + (rf * 16 + l15) * HSTR +
                              (((unsigned)(ks * 64 + l4 * 16)) ^ swz));
                #pragma unroll
                for (int cf = 0; cf < 4; ++cf)
                    acc[rf][cf] = __builtin_amdgcn_mfma_f32_16x16x32_bf16(
                        wb[t][cf], hf, acc[rf][cf], 0, 0, 0);
            }
            if (ks + 4 < NK2) {
                #pragma unroll
                for (int cf = 0; cf < 4; ++cf)
                    wb[t][cf] = W2FRAG(ks + 4, cf);
            }
        }
    }

    // ---------------- epilogue: bias + float4 stores ----------------
    #pragma unroll
    for (int cf = 0; cf < 4; ++cf) {
        const int colb = wcol + cf * 16 + l4 * 4;
        const f32x4 bb = *(const f32x4*)(b2 + colb);
        #pragma unroll
        for (int rf = 0; rf < 8; ++rf) {
            const int row = rowbase + rf * 16 + l15;
            f32x4 o = acc[rf][cf] + bb;
            *(f32x4*)(out + row * 512 + colb) = o;
        }
    }
}

extern "C" void kernel_launch(void* const* d_in, const int* in_sizes, int n_in,
                              void* d_out, int out_size, void* d_ws, size_t ws_size,
                              hipStream_t stream)
{
    (void)in_sizes; (void)n_in; (void)out_size; (void)ws_size;
    const float* pf  = (const float*)d_in[0];
    const float* pt  = (const float*)d_in[1];
    const float* nm  = (const float*)d_in[2];
    const float* Wsx = (const float*)d_in[3];
    const float* bsx = (const float*)d_in[4];
    const float* Wcx = (const float*)d_in[5];
    const float* bcx = (const float*)d_in[6];
    const float* Wsy = (const float*)d_in[7];
    const float* bsy = (const float*)d_in[8];
    const float* Wcy = (const float*)d_in[9];
    const float* bcy = (const float*)d_in[10];
    const float* Wn  = (const float*)d_in[11];
    const float* bn  = (const float*)d_in[12];
    const float* W1  = (const float*)d_in[13];
    const float* b1  = (const float*)d_in[14];
    const float* W2  = (const float*)d_in[15];
    const float* b2  = (const float*)d_in[16];

    unsigned char* ws = (unsigned char*)d_ws;
    unsigned short* w1bp = (unsigned short*)(ws);
    unsigned short* w2bp = (unsigned short*)(ws + 512 * 640 * 2);
    float* wf  = (float*)(ws + 512 * 640 * 2 + 512 * 512 * 2);
    float* bfv = (float*)(ws + 512 * 640 * 2 + 512 * 512 * 2 + 640 * 4);

    const int prep_threads = 512 * 640 + 512 * 512;
    prep_kernel<<<(prep_threads + 255) / 256, 256, 0, stream>>>(
        W1, W2, Wsx, bsx, Wcx, bcx, Wsy, bsy, Wcy, bcy, Wn, bn, w1bp, w2bp, wf, bfv);

    mlp_kernel<<<NROWS / BM, 512, 0, stream>>>(
        pf, pt, nm, w1bp, w2bp, wf, bfv, b1, b2, (float*)d_out);
}